// Round 2
// baseline (29.512 us; speedup 1.0000x reference)
//
#include <hip/hip_runtime.h>

// out[b,s,e] = cos(x[b,s,1]) * W_dec[e] + b_dec[e]
// x: (8, 4096, 1024) f32; W_dec: (1024,1) f32; b_dec: (1024,) f32
// out: (8, 4096, 1024) f32. Write-BW bound: 134 MB of stores.
// Fill-kernel calibration (R1 rocprof): pure write stream sustains ~7.1 TB/s.

#define EMBED 1024
#define ROWS_PER_BLOCK 16

template <bool GUARD>
__global__ __launch_bounds__(256) void vql_kernel(const float* __restrict__ x,
                                                  const float* __restrict__ W,
                                                  const float* __restrict__ b,
                                                  float* __restrict__ out,
                                                  int nrows) {
    const int tid = threadIdx.x;  // 256 threads * float4 = 1024 = one row
    const float4 w4 = reinterpret_cast<const float4*>(W)[tid];
    const float4 b4 = reinterpret_cast<const float4*>(b)[tid];

    const int row0 = blockIdx.x * ROWS_PER_BLOCK;

    if (!GUARD) {
        // Phase 1: batch all 16 uniform-address loads (no branches between
        // them -> all in flight simultaneously, one latency instead of 16).
        float xv[ROWS_PER_BLOCK];
#pragma unroll
        for (int r = 0; r < ROWS_PER_BLOCK; ++r)
            xv[r] = x[(size_t)(row0 + r) * EMBED + 1];

        // Phase 2: transcendental (off the store critical path).
        float c[ROWS_PER_BLOCK];
#pragma unroll
        for (int r = 0; r < ROWS_PER_BLOCK; ++r)
            c[r] = cosf(xv[r]);

        // Phase 3: 16 back-to-back coalesced float4 stores (fill-kernel-like
        // dependency-free write stream).
#pragma unroll
        for (int r = 0; r < ROWS_PER_BLOCK; ++r) {
            float4 o;
            o.x = fmaf(c[r], w4.x, b4.x);
            o.y = fmaf(c[r], w4.y, b4.y);
            o.z = fmaf(c[r], w4.z, b4.z);
            o.w = fmaf(c[r], w4.w, b4.w);
            reinterpret_cast<float4*>(out + (size_t)(row0 + r) * EMBED)[tid] = o;
        }
    } else {
        for (int r = 0; r < ROWS_PER_BLOCK; ++r) {
            const int row = row0 + r;
            if (row >= nrows) return;
            const float c = cosf(x[(size_t)row * EMBED + 1]);
            float4 o;
            o.x = fmaf(c, w4.x, b4.x);
            o.y = fmaf(c, w4.y, b4.y);
            o.z = fmaf(c, w4.z, b4.z);
            o.w = fmaf(c, w4.w, b4.w);
            reinterpret_cast<float4*>(out + (size_t)row * EMBED)[tid] = o;
        }
    }
}

extern "C" void kernel_launch(void* const* d_in, const int* in_sizes, int n_in,
                              void* d_out, int out_size, void* d_ws, size_t ws_size,
                              hipStream_t stream) {
    const float* x = (const float*)d_in[0];
    const float* W = (const float*)d_in[1];
    const float* b = (const float*)d_in[2];
    float* out = (float*)d_out;

    const int nrows = in_sizes[0] / EMBED;  // 8*4096 = 32768
    const int full_blocks = nrows / ROWS_PER_BLOCK;  // 2048, exact at this shape

    if (full_blocks > 0)
        vql_kernel<false><<<full_blocks, 256, 0, stream>>>(x, W, b, out, nrows);

    const int tail_rows = nrows - full_blocks * ROWS_PER_BLOCK;
    if (tail_rows > 0) {
        const float* x_t = x + (size_t)full_blocks * ROWS_PER_BLOCK * EMBED;
        float* out_t = out + (size_t)full_blocks * ROWS_PER_BLOCK * EMBED;
        vql_kernel<true><<<1, 256, 0, stream>>>(x_t, W, b, out_t, tail_rows);
    }
}